// Round 10
// baseline (259.467 us; speedup 1.0000x reference)
//
#include <hip/hip_runtime.h>

#define C_DIM 768
#define NSEQ 2048
#define H_DIM 12
#define HD 64
#define M_ROWS 4096   // B*N
#define KSPLIT 4      // each attn block handles NSEQ/KSPLIT keys

typedef float f32x4 __attribute__((ext_vector_type(4)));
typedef short bf16x8 __attribute__((ext_vector_type(8)));
typedef _Float16 f16x8 __attribute__((ext_vector_type(8)));
typedef _Float16 f16x4 __attribute__((ext_vector_type(4)));
typedef __fp16 fp16x2 __attribute__((ext_vector_type(2)));  // cvt_pkrtz return type
typedef __fp16 fp16x4 __attribute__((ext_vector_type(4)));
typedef __fp16 fp16x8 __attribute__((ext_vector_type(8)));
typedef unsigned short u16;

// NOTE: legacy K=16 f16 MFMA builtin has NO underscore before f16 on gfx950.
#define MFMA_PV(a, b, c) __builtin_amdgcn_mfma_f32_16x16x16f16(a, b, c, 0, 0, 0)

typedef unsigned int __attribute__((address_space(1))) as1_uint;
typedef unsigned int __attribute__((address_space(3))) as3_uint;
// async global->LDS DMA, 16B per lane; LDS dest = wave-uniform base + lane*16
__device__ __forceinline__ void dma16(const void* g, void* l) {
  __builtin_amdgcn_global_load_lds((const as1_uint*)g, (as3_uint*)l, 16, 0, 0);
}

__device__ __forceinline__ u16 f2bf(float f) {
  union { float f; unsigned u; } v; v.f = f;
  unsigned u = v.u + 0x7FFFu + ((v.u >> 16) & 1u);  // RNE
  return (u16)(u >> 16);
}

// ---------------- fused prep: weight transposes + x conversion ----------------
// z=0: w_qkv^T (bf16); z=1: w_proj^T (f16); z=2: x fp32->bf16
__global__ __launch_bounds__(256) void prep_kernel(const float* __restrict__ x,
                                                   const float* __restrict__ wq,
                                                   const float* __restrict__ wp,
                                                   u16* __restrict__ x_bf,
                                                   u16* __restrict__ outq,
                                                   __fp16* __restrict__ outp) {
  if (blockIdx.z == 2) {
    const int n4 = M_ROWS * C_DIM / 4;
    int lb = blockIdx.y * 72 + blockIdx.x;          // 0..1727
    int i0 = lb * 256 + threadIdx.x;                // < 442368
    {
      float4 v = ((const float4*)x)[i0];
      ushort4 o;
      o.x = f2bf(v.x); o.y = f2bf(v.y); o.z = f2bf(v.z); o.w = f2bf(v.w);
      ((ushort4*)x_bf)[i0] = o;
    }
    int i1 = i0 + 442368;
    if (i1 < n4) {
      float4 v = ((const float4*)x)[i1];
      ushort4 o;
      o.x = f2bf(v.x); o.y = f2bf(v.y); o.z = f2bf(v.z); o.w = f2bf(v.w);
      ((ushort4*)x_bf)[i1] = o;
    }
    return;
  }
  const int R = C_DIM;
  __shared__ float t[32][33];
  int tx = threadIdx.x & 31, ty = threadIdx.x >> 5;  // 32 x 8
  int c0 = blockIdx.x * 32, r0 = blockIdx.y * 32;
  if (blockIdx.z == 0) {
    const int Cc = 3 * C_DIM;
#pragma unroll
    for (int i = 0; i < 4; i++)
      t[ty + i * 8][tx] = wq[(size_t)(r0 + ty + i * 8) * Cc + c0 + tx];
    __syncthreads();
#pragma unroll
    for (int i = 0; i < 4; i++)
      outq[(size_t)(c0 + ty + i * 8) * R + r0 + tx] = f2bf(t[tx][ty + i * 8]);
  } else {
    if (blockIdx.x >= 24) return;
    const int Cc = C_DIM;
#pragma unroll
    for (int i = 0; i < 4; i++)
      t[ty + i * 8][tx] = wp[(size_t)(r0 + ty + i * 8) * Cc + c0 + tx];
    __syncthreads();
#pragma unroll
    for (int i = 0; i < 4; i++)
      outp[(size_t)(c0 + ty + i * 8) * R + r0 + tx] = (__fp16)t[tx][ty + i * 8];
  }
}

// ------- 128x128 bf16 MFMA GEMM core, double-buffered global_load_lds --------
__device__ __forceinline__ void gemm_core_128_db(const u16* __restrict__ A,
                                                 const u16* __restrict__ BT,
                                                 int m0, int n0,
                                                 u16 (*la)[128 * 32], u16 (*lb)[128 * 32],
                                                 f32x4 acc[4][4]) {
  const int K = C_DIM;
  int tid = threadIdx.x, lane = tid & 63, wave = tid >> 6;
  int wm = (wave >> 1) * 64, wn = (wave & 1) * 64;
  int quad = lane >> 4, l16 = lane & 15;

  int r0 = wave * 16 + (lane >> 2);
  int sw = (((lane & 3) ^ (r0 & 3)) * 8);   // (r0+64)&3 == r0&3
  const u16* ga0 = A + (size_t)(m0 + r0) * K + sw;
  const u16* ga1 = A + (size_t)(m0 + r0 + 64) * K + sw;
  const u16* gb0 = BT + (size_t)(n0 + r0) * K + sw;
  const u16* gb1 = BT + (size_t)(n0 + r0 + 64) * K + sw;
  int ofs0 = wave * 16 * 32, ofs1 = ofs0 + 64 * 32;  // wave-uniform LDS offsets

  dma16(ga0, la[0] + ofs0);
  dma16(ga1, la[0] + ofs1);
  dma16(gb0, lb[0] + ofs0);
  dma16(gb1, lb[0] + ofs1);

  const int NT = K / 32;  // 24
  for (int kt = 0; kt < NT; kt++) {
    int cur = kt & 1, nxt = cur ^ 1;
    __syncthreads();
    if (kt < NT - 1) {
      int k0 = (kt + 1) * 32;
      dma16(ga0 + k0, la[nxt] + ofs0);
      dma16(ga1 + k0, la[nxt] + ofs1);
      dma16(gb0 + k0, lb[nxt] + ofs0);
      dma16(gb1 + k0, lb[nxt] + ofs1);
    }
    bf16x8 af[4], bfr[4];
#pragma unroll
    for (int mt = 0; mt < 4; mt++) {
      int r = wm + mt * 16 + l16;
      af[mt] = *(const bf16x8*)(la[cur] + r * 32 + ((quad ^ (r & 3)) * 8));
    }
#pragma unroll
    for (int nt = 0; nt < 4; nt++) {
      int r = wn + nt * 16 + l16;
      bfr[nt] = *(const bf16x8*)(lb[cur] + r * 32 + ((quad ^ (r & 3)) * 8));
    }
#pragma unroll
    for (int mt = 0; mt < 4; mt++)
#pragma unroll
      for (int nt = 0; nt < 4; nt++)
        acc[mt][nt] = __builtin_amdgcn_mfma_f32_16x16x32_bf16(af[mt], bfr[nt], acc[mt][nt], 0, 0, 0);
  }
}

// ---------------- GEMM1: qkv = x @ w_qkv, scatter into f16 q/k/v^T ----------------
#define Q_PRESCALE 0.18033688011112042f  // HD^-0.5 * log2(e)
__global__ __launch_bounds__(256) void gemm_qkv_kernel(const u16* __restrict__ A,
                                                       const u16* __restrict__ BT,
                                                       _Float16* __restrict__ qb,
                                                       _Float16* __restrict__ kb,
                                                       _Float16* __restrict__ vtb) {
  __shared__ __align__(16) u16 la[2][128 * 32];
  __shared__ __align__(16) u16 lb[2][128 * 32];
  f32x4 acc[4][4] = {};
  int m0 = blockIdx.x * 128, n0 = blockIdx.y * 128;
  gemm_core_128_db(A, BT, m0, n0, la, lb, acc);

  int lane = threadIdx.x & 63, wave = threadIdx.x >> 6;
  int wm = (wave >> 1) * 64, wn = (wave & 1) * 64;
  int quad = lane >> 4, l16 = lane & 15;
#pragma unroll
  for (int mt = 0; mt < 4; mt++) {
#pragma unroll
    for (int nt = 0; nt < 4; nt++) {
      int gn = n0 + wn + nt * 16 + l16;       // 0..2303
      int which = gn / C_DIM;                 // 0=q 1=k 2=v (uniform per block)
      int cc = gn - which * C_DIM;
      int h = cc >> 6, d = cc & 63;
      int gm0 = m0 + wm + mt * 16 + quad * 4;  // 4-aligned, never crosses b-boundary
      int b = gm0 >> 11, n = gm0 & 2047;
      size_t bh = (size_t)(b * H_DIM + h);
      if (which == 2) {
        f16x4 hv;
#pragma unroll
        for (int r = 0; r < 4; r++) hv[r] = (_Float16)acc[mt][nt][r];
        *(f16x4*)(vtb + (bh * HD + d) * NSEQ + n) = hv;  // v^T, 4 consecutive n
      } else if (which == 0) {
#pragma unroll
        for (int r = 0; r < 4; r++)
          qb[(bh * NSEQ + n + r) * HD + d] = (_Float16)(acc[mt][nt][r] * Q_PRESCALE);
      } else {
#pragma unroll
        for (int r = 0; r < 4; r++)
          kb[(bh * NSEQ + n + r) * HD + d] = (_Float16)acc[mt][nt][r];
      }
    }
  }
}

// ------- GEMM3 fused with combine: out = (sum_ks o / sum_ks l) @ w_proj + b -------
__global__ __launch_bounds__(256) void gemm_proj_kernel(const __fp16* __restrict__ opart,
                                                        const float* __restrict__ lpart,
                                                        const u16* __restrict__ BT,
                                                        const float* __restrict__ bias,
                                                        float* __restrict__ out) {
  __shared__ __align__(16) u16 la[2][64 * 32];
  __shared__ __align__(16) u16 lb[2][128 * 32];
  int tid = threadIdx.x, lane = tid & 63, wave = tid >> 6;
  int quad = lane >> 4, l16 = lane & 15;
  int wm = (wave >> 1) * 32, wn = (wave & 1) * 64;
  int m0 = blockIdx.x * 64, n0 = blockIdx.y * 128;

  // B DMA geometry
  int r0 = wave * 16 + (lane >> 2);
  int swb = (((lane & 3) ^ (r0 & 3)) * 8);
  const u16* gb0 = BT + (size_t)(n0 + r0) * C_DIM + swb;
  const u16* gb1 = BT + (size_t)(n0 + r0 + 64) * C_DIM + swb;
  int ofsB0 = wave * 16 * 32, ofsB1 = ofsB0 + 64 * 32;

  // A staging role: row ar (0..63), chunk cj (0..3); combine KSPLIT partials
  int ar = r0, cj = lane & 3;
  int m = m0 + ar;
  int bb = m >> 11, q = m & 2047;
  const __fp16* ap = opart + (size_t)m * C_DIM + cj * 8;
  int wslotA = ar * 32 + ((cj ^ (ar & 3)) * 8);

  f32x4 acc[2][4] = {};
  union pk_t { fp16x2 h2[4]; uint4 v; };

#define COMBINE_A(dstbuf, k0, hh)                                              \
  {                                                                            \
    float fs[8] = {0, 0, 0, 0, 0, 0, 0, 0};                                    \
    float l = 0.f;                                                             \
    _Pragma("unroll") for (int kk = 0; kk < KSPLIT; kk++) {                    \
      fp16x8 pv = *(const fp16x8*)(ap + (size_t)kk * M_ROWS * C_DIM + (k0));   \
      _Pragma("unroll") for (int j = 0; j < 8; j++) fs[j] += (float)pv[j];     \
      l += lpart[((size_t)kk * H_DIM * 2 + bb * H_DIM + (hh)) * NSEQ + q];     \
    }                                                                          \
    float inv = 1.f / l;                                                       \
    pk_t w;                                                                    \
    _Pragma("unroll") for (int j = 0; j < 4; j++)                              \
        w.h2[j] = __builtin_amdgcn_cvt_pkrtz(fs[2 * j] * inv, fs[2 * j + 1] * inv); \
    *(uint4*)(la[dstbuf] + wslotA) = w.v;                                      \
  }

  // prologue: tile 0
  dma16(gb0, lb[0] + ofsB0);
  dma16(gb1, lb[0] + ofsB1);
  COMBINE_A(0, 0, 0);

  const int NT = C_DIM / 32;  // 24
  for (int kt = 0; kt < NT; kt++) {
    int cur = kt & 1, nxt = cur ^ 1;
    __syncthreads();
    if (kt < NT - 1) {
      int k0 = (kt + 1) * 32;
      dma16(gb0 + k0, lb[nxt] + ofsB0);
      dma16(gb1 + k0, lb[nxt] + ofsB1);
      COMBINE_A(nxt, k0, (kt + 1) >> 1);
    }
    f16x8 af[2], bf[4];
#pragma unroll
    for (int mt = 0; mt < 2; mt++) {
      int r = wm + mt * 16 + l16;
      af[mt] = *(const f16x8*)(la[cur] + r * 32 + ((quad ^ (r & 3)) * 8));
    }
#pragma unroll
    for (int nt = 0; nt < 4; nt++) {
      int r = wn + nt * 16 + l16;
      bf[nt] = *(const f16x8*)(lb[cur] + r * 32 + ((quad ^ (r & 3)) * 8));
    }
#pragma unroll
    for (int mt = 0; mt < 2; mt++)
#pragma unroll
      for (int nt = 0; nt < 4; nt++)
        acc[mt][nt] = __builtin_amdgcn_mfma_f32_16x16x32_f16(af[mt], bf[nt], acc[mt][nt], 0, 0, 0);
  }

#pragma unroll
  for (int mt = 0; mt < 2; mt++) {
#pragma unroll
    for (int nt = 0; nt < 4; nt++) {
      int gn = n0 + wn + nt * 16 + l16;
      float bv = bias[gn];
#pragma unroll
      for (int r = 0; r < 4; r++) {
        int gm = m0 + wm + mt * 16 + quad * 4 + r;
        out[(size_t)gm * C_DIM + gn] = acc[mt][nt][r] + bv;
      }
    }
  }
}

// ---------------- flash attention: NO-LDS, S^T formulation ----------------
// Both MFMA operand layouts coincide with global layouts:
//   K-frag (A: m=key,k=d)  = 16 contiguous rows of kb   -> f16x8 global load
//   V-frag (A: m=d,k=key)  = 16 rows x 8B of vtb        -> f16x4 global load
// So fragments load straight from global (K+V = 12 MB, L2/L3-resident).
// Zero LDS, zero barriers, zero bank conflicts. 4 q-tiles/wave (64 q) halves
// K/V re-read redundancy; KSPLIT=4 keeps grid at 768 = 3 blocks/CU.
__global__ __launch_bounds__(256, 3) void attn_kernel(const _Float16* __restrict__ qb,
                                                      const _Float16* __restrict__ kb,
                                                      const _Float16* __restrict__ vtb,
                                                      __fp16* __restrict__ opart,
                                                      float* __restrict__ lpart) {
  int bh = blockIdx.y, qblk = blockIdx.x, ks = blockIdx.z;
  int tid = threadIdx.x, lane = tid & 63, wave = tid >> 6;
  int quad = lane >> 4, l16 = lane & 15;

  const _Float16* q_bh = qb + (size_t)bh * NSEQ * HD;
  const _Float16* k_bh = kb + (size_t)bh * NSEQ * HD;
  const _Float16* v_bh = vtb + (size_t)bh * HD * NSEQ;

  // Q fragments (B-layout: n=l16, k=quad*8+j), 4 q-tiles per wave
  int q0 = qblk * 256 + wave * 64 + l16;
  f16x8 qf[4][2];
#pragma unroll
  for (int qt = 0; qt < 4; qt++) {
    const _Float16* qp = q_bh + (size_t)(q0 + qt * 16) * HD + quad * 8;
    qf[qt][0] = *(const f16x8*)qp;
    qf[qt][1] = *(const f16x8*)(qp + 32);
  }

  f32x4 o[4][4] = {};
  float l_i[4] = {0.f, 0.f, 0.f, 0.f};

  const int kbase = ks * (NSEQ / KSPLIT);           // 512 keys per block
  const _Float16* kR = k_bh + (size_t)(kbase + l16) * HD + quad * 8;
  const _Float16* vB[4];
#pragma unroll
  for (int dt = 0; dt < 4; dt++)
    vB[dt] = v_bh + (size_t)(dt * 16 + l16) * NSEQ + kbase + quad * 4;

  const int NKT = NSEQ / 64 / KSPLIT;               // 8 tiles
  for (int kt = 0; kt < NKT; kt++) {
#pragma unroll
    for (int nt = 0; nt < 4; nt++) {
      int koff = kt * 64 + nt * 16;
      // K fragment straight from global (16 rows x 16B, contiguous lines)
      const _Float16* kp = kR + (size_t)koff * HD;
      f16x8 kf0 = *(const f16x8*)kp;
      f16x8 kf1 = *(const f16x8*)(kp + 32);
      // V fragments for this nt (issued early; consumed after exp)
      f16x4 vf[4];
#pragma unroll
      for (int dt = 0; dt < 4; dt++) vf[dt] = *(const f16x4*)(vB[dt] + koff);
      // S^T = K·Q^T : lane gets keys {nt*16+quad*4+r}, query l16
      f32x4 s[4];
#pragma unroll
      for (int qt = 0; qt < 4; qt++) {
        f32x4 t = {};
        t = __builtin_amdgcn_mfma_f32_16x16x32_f16(kf0, qf[qt][0], t, 0, 0, 0);
        t = __builtin_amdgcn_mfma_f32_16x16x32_f16(kf1, qf[qt][1], t, 0, 0, 0);
        s[qt] = t;
      }
      // p = 2^s (scale folded into q); l per-lane; P^T straight to PV B-operand
      f16x4 p[4];
#pragma unroll
      for (int qt = 0; qt < 4; qt++) {
        float e0 = __builtin_amdgcn_exp2f(s[qt][0]);
        float e1 = __builtin_amdgcn_exp2f(s[qt][1]);
        float e2 = __builtin_amdgcn_exp2f(s[qt][2]);
        float e3 = __builtin_amdgcn_exp2f(s[qt][3]);
        l_i[qt] += (e0 + e1) + (e2 + e3);
        union { fp16x2 h2[2]; f16x4 h4; } u;
        u.h2[0] = __builtin_amdgcn_cvt_pkrtz(e0, e1);
        u.h2[1] = __builtin_amdgcn_cvt_pkrtz(e2, e3);
        p[qt] = u.h4;
      }
#pragma unroll
      for (int dt = 0; dt < 4; dt++)
#pragma unroll
        for (int qt = 0; qt < 4; qt++)
          o[qt][dt] = MFMA_PV(vf[dt], p[qt], o[qt][dt]);
    }
  }

  // partial denominator: quads hold disjoint key subsets for query l16
#pragma unroll
  for (int qt = 0; qt < 4; qt++) {
    l_i[qt] += __shfl_xor(l_i[qt], 16);
    l_i[qt] += __shfl_xor(l_i[qt], 32);
  }

  int b = bh / H_DIM, h = bh % H_DIM;
  __fp16* obase = opart + (size_t)ks * M_ROWS * C_DIM;
  float* lrow = lpart + ((size_t)ks * H_DIM * 2 + bh) * NSEQ;
#pragma unroll
  for (int qt = 0; qt < 4; qt++) {
    int q = q0 + qt * 16;  // query index (l16-dependent)
    if (quad == 0) lrow[q] = l_i[qt];
    __fp16* orow = obase + (size_t)(b * NSEQ + q) * C_DIM + h * HD;
#pragma unroll
    for (int dt = 0; dt < 4; dt++) {
      union { fp16x2 h2[2]; fp16x4 h4; } ov;
      ov.h2[0] = __builtin_amdgcn_cvt_pkrtz(o[qt][dt][0], o[qt][dt][1]);
      ov.h2[1] = __builtin_amdgcn_cvt_pkrtz(o[qt][dt][2], o[qt][dt][3]);
      *(fp16x4*)(orow + dt * 16 + quad * 4) = ov.h4;  // O^T d=dt*16+quad*4+reg
    }
  }
}

extern "C" void kernel_launch(void* const* d_in, const int* in_sizes, int n_in,
                              void* d_out, int out_size, void* d_ws, size_t ws_size,
                              hipStream_t stream) {
  const float* x = (const float*)d_in[0];       // [2,2048,768]
  const float* w_qkv = (const float*)d_in[1];   // [768,2304]
  const float* w_proj = (const float*)d_in[2];  // [768,768]
  const float* b_proj = (const float*)d_in[3];  // [768]
  float* out = (float*)d_out;

  char* ws = (char*)d_ws;
  u16* x_bf        = (u16*)(ws);                  // 4096*768*2   = 6291456
  u16* wqkvT       = (u16*)(ws + 6291456);        // 2304*768*2   = 3538944
  __fp16* wprojT   = (__fp16*)(ws + 9830400);     // 768*768*2    = 1179648
  _Float16* qb     = (_Float16*)(ws + 11010048);  // 24*2048*64*2 = 6291456
  _Float16* kb     = (_Float16*)(ws + 17301504);
  _Float16* vtb    = (_Float16*)(ws + 23592960);  // ends at 29884416
  __fp16* opart    = (__fp16*)(ws + 29884416);    // 4*4096*768*2 = 25165824
  float* lpart     = (float*)(ws + 55050240);     // 4*24*2048*4  = 786432 -> ends 55836672

  prep_kernel<<<dim3(72, 24, 3), 256, 0, stream>>>(x, w_qkv, w_proj, x_bf, wqkvT, wprojT);
  gemm_qkv_kernel<<<dim3(32, 18), 256, 0, stream>>>(x_bf, wqkvT, qb, kb, vtb);
  attn_kernel<<<dim3(8, 24, KSPLIT), 256, 0, stream>>>(qb, kb, vtb, opart, lpart);
  gemm_proj_kernel<<<dim3(64, 6), 256, 0, stream>>>(opart, lpart, (const u16*)wprojT,
                                                    b_proj, out);
}

// Round 11
// 191.340 us; speedup vs baseline: 1.3560x; 1.3560x over previous
//
#include <hip/hip_runtime.h>

#define C_DIM 768
#define NSEQ 2048
#define H_DIM 12
#define HD 64
#define M_ROWS 4096   // B*N
#define KSPLIT 2      // each attn block handles NSEQ/KSPLIT keys
#define PADK 76       // LDS row stride (u16): 38 dwords -> ~2-way (free) conflicts

typedef float f32x4 __attribute__((ext_vector_type(4)));
typedef short bf16x8 __attribute__((ext_vector_type(8)));
typedef _Float16 f16x8 __attribute__((ext_vector_type(8)));
typedef _Float16 f16x4 __attribute__((ext_vector_type(4)));
typedef __fp16 fp16x2 __attribute__((ext_vector_type(2)));  // cvt_pkrtz return type
typedef __fp16 fp16x4 __attribute__((ext_vector_type(4)));
typedef __fp16 fp16x8 __attribute__((ext_vector_type(8)));
typedef unsigned short u16;

// NOTE: legacy K=16 f16 MFMA builtin has NO underscore before f16 on gfx950.
#define MFMA_PV(a, b, c) __builtin_amdgcn_mfma_f32_16x16x16f16(a, b, c, 0, 0, 0)

typedef unsigned int __attribute__((address_space(1))) as1_uint;
typedef unsigned int __attribute__((address_space(3))) as3_uint;
// async global->LDS DMA, 16B per lane; LDS dest = wave-uniform base + lane*16
__device__ __forceinline__ void dma16(const void* g, void* l) {
  __builtin_amdgcn_global_load_lds((const as1_uint*)g, (as3_uint*)l, 16, 0, 0);
}

__device__ __forceinline__ u16 f2bf(float f) {
  union { float f; unsigned u; } v; v.f = f;
  unsigned u = v.u + 0x7FFFu + ((v.u >> 16) & 1u);  // RNE
  return (u16)(u >> 16);
}

// ---------------- fused prep: weight transposes + x conversion ----------------
// z=0: w_qkv^T (bf16); z=1: w_proj^T (f16); z=2: x fp32->bf16
__global__ __launch_bounds__(256) void prep_kernel(const float* __restrict__ x,
                                                   const float* __restrict__ wq,
                                                   const float* __restrict__ wp,
                                                   u16* __restrict__ x_bf,
                                                   u16* __restrict__ outq,
                                                   __fp16* __restrict__ outp) {
  if (blockIdx.z == 2) {
    const int n4 = M_ROWS * C_DIM / 4;
    int lb = blockIdx.y * 72 + blockIdx.x;          // 0..1727
    int i0 = lb * 256 + threadIdx.x;                // < 442368
    {
      float4 v = ((const float4*)x)[i0];
      ushort4 o;
      o.x = f2bf(v.x); o.y = f2bf(v.y); o.z = f2bf(v.z); o.w = f2bf(v.w);
      ((ushort4*)x_bf)[i0] = o;
    }
    int i1 = i0 + 442368;
    if (i1 < n4) {
      float4 v = ((const float4*)x)[i1];
      ushort4 o;
      o.x = f2bf(v.x); o.y = f2bf(v.y); o.z = f2bf(v.z); o.w = f2bf(v.w);
      ((ushort4*)x_bf)[i1] = o;
    }
    return;
  }
  const int R = C_DIM;
  __shared__ float t[32][33];
  int tx = threadIdx.x & 31, ty = threadIdx.x >> 5;  // 32 x 8
  int c0 = blockIdx.x * 32, r0 = blockIdx.y * 32;
  if (blockIdx.z == 0) {
    const int Cc = 3 * C_DIM;
#pragma unroll
    for (int i = 0; i < 4; i++)
      t[ty + i * 8][tx] = wq[(size_t)(r0 + ty + i * 8) * Cc + c0 + tx];
    __syncthreads();
#pragma unroll
    for (int i = 0; i < 4; i++)
      outq[(size_t)(c0 + ty + i * 8) * R + r0 + tx] = f2bf(t[tx][ty + i * 8]);
  } else {
    if (blockIdx.x >= 24) return;
    const int Cc = C_DIM;
#pragma unroll
    for (int i = 0; i < 4; i++)
      t[ty + i * 8][tx] = wp[(size_t)(r0 + ty + i * 8) * Cc + c0 + tx];
    __syncthreads();
#pragma unroll
    for (int i = 0; i < 4; i++)
      outp[(size_t)(c0 + ty + i * 8) * R + r0 + tx] = (__fp16)t[tx][ty + i * 8];
  }
}

// ------- 128x128 bf16 MFMA GEMM core, double-buffered global_load_lds --------
// SWAPPED operands: acc[mt][nt] = B_tile^T-block x A-block = C^T. In C^T layout
// each lane holds 4 consecutive OUTPUT-CHANNEL values (row=quad*4+r) for a
// fixed token (col=l16) -> enables vectorized channel-contiguous epilogues.
__device__ __forceinline__ void gemm_core_128_db(const u16* __restrict__ A,
                                                 const u16* __restrict__ BT,
                                                 int m0, int n0,
                                                 u16 (*la)[128 * 32], u16 (*lb)[128 * 32],
                                                 f32x4 acc[4][4]) {
  const int K = C_DIM;
  int tid = threadIdx.x, lane = tid & 63, wave = tid >> 6;
  int wm = (wave >> 1) * 64, wn = (wave & 1) * 64;
  int quad = lane >> 4, l16 = lane & 15;

  int r0 = wave * 16 + (lane >> 2);
  int sw = (((lane & 3) ^ (r0 & 3)) * 8);   // (r0+64)&3 == r0&3
  const u16* ga0 = A + (size_t)(m0 + r0) * K + sw;
  const u16* ga1 = A + (size_t)(m0 + r0 + 64) * K + sw;
  const u16* gb0 = BT + (size_t)(n0 + r0) * K + sw;
  const u16* gb1 = BT + (size_t)(n0 + r0 + 64) * K + sw;
  int ofs0 = wave * 16 * 32, ofs1 = ofs0 + 64 * 32;  // wave-uniform LDS offsets

  dma16(ga0, la[0] + ofs0);
  dma16(ga1, la[0] + ofs1);
  dma16(gb0, lb[0] + ofs0);
  dma16(gb1, lb[0] + ofs1);

  const int NT = K / 32;  // 24
  for (int kt = 0; kt < NT; kt++) {
    int cur = kt & 1, nxt = cur ^ 1;
    __syncthreads();
    if (kt < NT - 1) {
      int k0 = (kt + 1) * 32;
      dma16(ga0 + k0, la[nxt] + ofs0);
      dma16(ga1 + k0, la[nxt] + ofs1);
      dma16(gb0 + k0, lb[nxt] + ofs0);
      dma16(gb1 + k0, lb[nxt] + ofs1);
    }
    bf16x8 af[4], bfr[4];
#pragma unroll
    for (int mt = 0; mt < 4; mt++) {
      int r = wm + mt * 16 + l16;
      af[mt] = *(const bf16x8*)(la[cur] + r * 32 + ((quad ^ (r & 3)) * 8));
    }
#pragma unroll
    for (int nt = 0; nt < 4; nt++) {
      int r = wn + nt * 16 + l16;
      bfr[nt] = *(const bf16x8*)(lb[cur] + r * 32 + ((quad ^ (r & 3)) * 8));
    }
#pragma unroll
    for (int mt = 0; mt < 4; mt++)
#pragma unroll
      for (int nt = 0; nt < 4; nt++)   // SWAPPED: C^T
        acc[mt][nt] = __builtin_amdgcn_mfma_f32_16x16x32_bf16(bfr[nt], af[mt], acc[mt][nt], 0, 0, 0);
  }
}

// ---------------- GEMM1: qkv = x @ w_qkv, scatter into f16 q/k/v^T ----------------
// C^T layout: lane has 4 consecutive channels (gn0..gn0+3) for one token gm.
#define Q_PRESCALE 0.18033688011112042f  // HD^-0.5 * log2(e)
__global__ __launch_bounds__(256) void gemm_qkv_kernel(const u16* __restrict__ A,
                                                       const u16* __restrict__ BT,
                                                       _Float16* __restrict__ qb,
                                                       _Float16* __restrict__ kb,
                                                       _Float16* __restrict__ vtb) {
  __shared__ __align__(16) u16 la[2][128 * 32];
  __shared__ __align__(16) u16 lb[2][128 * 32];
  f32x4 acc[4][4] = {};
  int m0 = blockIdx.x * 128, n0 = blockIdx.y * 128;
  gemm_core_128_db(A, BT, m0, n0, la, lb, acc);

  int lane = threadIdx.x & 63, wave = threadIdx.x >> 6;
  int wm = (wave >> 1) * 64, wn = (wave & 1) * 64;
  int quad = lane >> 4, l16 = lane & 15;
#pragma unroll
  for (int mt = 0; mt < 4; mt++) {
#pragma unroll
    for (int nt = 0; nt < 4; nt++) {
      int gm = m0 + wm + mt * 16 + l16;        // token 0..4095
      int b = gm >> 11, n = gm & 2047;
      int gn0 = n0 + wn + nt * 16 + quad * 4;  // channel base, 4-aligned
      int which = gn0 / C_DIM;                 // uniform per block
      int cc = gn0 - which * C_DIM;
      int h = cc >> 6, d0 = cc & 63;           // 4-block never crosses head bdry
      size_t bh = (size_t)(b * H_DIM + h);
      if (which == 2) {
#pragma unroll
        for (int r = 0; r < 4; r++)
          vtb[(bh * HD + d0 + r) * NSEQ + n] = (_Float16)acc[mt][nt][r];  // v^T
      } else if (which == 0) {
        f16x4 hv;
#pragma unroll
        for (int r = 0; r < 4; r++) hv[r] = (_Float16)(acc[mt][nt][r] * Q_PRESCALE);
        *(f16x4*)(qb + (bh * NSEQ + n) * HD + d0) = hv;   // 4 consecutive d
      } else {
        f16x4 hv;
#pragma unroll
        for (int r = 0; r < 4; r++) hv[r] = (_Float16)acc[mt][nt][r];
        *(f16x4*)(kb + (bh * NSEQ + n) * HD + d0) = hv;
      }
    }
  }
}

// ------- GEMM3 fused with combine: out = (sum_ks o / sum_ks l) @ w_proj + b -------
// 64x128 tiles, C^T accumulators -> float4 output stores + float4 bias loads.
__global__ __launch_bounds__(256) void gemm_proj_kernel(const __fp16* __restrict__ opart,
                                                        const float* __restrict__ lpart,
                                                        const u16* __restrict__ BT,
                                                        const float* __restrict__ bias,
                                                        float* __restrict__ out) {
  __shared__ __align__(16) u16 la[2][64 * 32];
  __shared__ __align__(16) u16 lb[2][128 * 32];
  int tid = threadIdx.x, lane = tid & 63, wave = tid >> 6;
  int quad = lane >> 4, l16 = lane & 15;
  int wm = (wave >> 1) * 32, wn = (wave & 1) * 64;
  int m0 = blockIdx.x * 64, n0 = blockIdx.y * 128;

  // B DMA geometry
  int r0 = wave * 16 + (lane >> 2);
  int swb = (((lane & 3) ^ (r0 & 3)) * 8);
  const u16* gb0 = BT + (size_t)(n0 + r0) * C_DIM + swb;
  const u16* gb1 = BT + (size_t)(n0 + r0 + 64) * C_DIM + swb;
  int ofsB0 = wave * 16 * 32, ofsB1 = ofsB0 + 64 * 32;

  // A staging role: row ar (0..63), chunk cj (0..3); combine KSPLIT partials
  int ar = r0, cj = lane & 3;
  int m = m0 + ar;
  int bb = m >> 11, q = m & 2047;
  const __fp16* ap = opart + (size_t)m * C_DIM + cj * 8;
  int wslotA = ar * 32 + ((cj ^ (ar & 3)) * 8);

  f32x4 acc[2][4] = {};
  union pk_t { fp16x2 h2[4]; uint4 v; };

#define COMBINE_A(dstbuf, k0, hh)                                              \
  {                                                                            \
    float fs[8] = {0, 0, 0, 0, 0, 0, 0, 0};                                    \
    float l = 0.f;                                                             \
    _Pragma("unroll") for (int kk = 0; kk < KSPLIT; kk++) {                    \
      fp16x8 pv = *(const fp16x8*)(ap + (size_t)kk * M_ROWS * C_DIM + (k0));   \
      _Pragma("unroll") for (int j = 0; j < 8; j++) fs[j] += (float)pv[j];     \
      l += lpart[((size_t)kk * H_DIM * 2 + bb * H_DIM + (hh)) * NSEQ + q];     \
    }                                                                          \
    float inv = 1.f / l;                                                       \
    pk_t w;                                                                    \
    _Pragma("unroll") for (int j = 0; j < 4; j++)                              \
        w.h2[j] = __builtin_amdgcn_cvt_pkrtz(fs[2 * j] * inv, fs[2 * j + 1] * inv); \
    *(uint4*)(la[dstbuf] + wslotA) = w.v;                                      \
  }

  // prologue: tile 0
  dma16(gb0, lb[0] + ofsB0);
  dma16(gb1, lb[0] + ofsB1);
  COMBINE_A(0, 0, 0);

  const int NT = C_DIM / 32;  // 24
  for (int kt = 0; kt < NT; kt++) {
    int cur = kt & 1, nxt = cur ^ 1;
    __syncthreads();
    if (kt < NT - 1) {
      int k0 = (kt + 1) * 32;
      dma16(gb0 + k0, lb[nxt] + ofsB0);
      dma16(gb1 + k0, lb[nxt] + ofsB1);
      COMBINE_A(nxt, k0, (kt + 1) >> 1);
    }
    f16x8 af[2], bf[4];
#pragma unroll
    for (int mt = 0; mt < 2; mt++) {
      int r = wm + mt * 16 + l16;
      af[mt] = *(const f16x8*)(la[cur] + r * 32 + ((quad ^ (r & 3)) * 8));
    }
#pragma unroll
    for (int nt = 0; nt < 4; nt++) {
      int r = wn + nt * 16 + l16;
      bf[nt] = *(const f16x8*)(lb[cur] + r * 32 + ((quad ^ (r & 3)) * 8));
    }
#pragma unroll
    for (int mt = 0; mt < 2; mt++)
#pragma unroll
      for (int nt = 0; nt < 4; nt++)   // SWAPPED: C^T
        acc[mt][nt] = __builtin_amdgcn_mfma_f32_16x16x32_f16(bf[nt], af[mt], acc[mt][nt], 0, 0, 0);
  }

#pragma unroll
  for (int mt = 0; mt < 2; mt++) {
#pragma unroll
    for (int nt = 0; nt < 4; nt++) {
      int gm = m0 + wm + mt * 16 + l16;
      int gn0 = n0 + wn + nt * 16 + quad * 4;
      float4 bv = *(const float4*)(bias + gn0);
      float4 o4;
      o4.x = acc[mt][nt][0] + bv.x;
      o4.y = acc[mt][nt][1] + bv.y;
      o4.z = acc[mt][nt][2] + bv.z;
      o4.w = acc[mt][nt][3] + bv.w;
      *(float4*)(out + (size_t)gm * C_DIM + gn0) = o4;
    }
  }
}

// ---------------- flash attention, S^T formulation, key-split 2 ----------------
// 256 thr, 4 waves x 2 q-tiles = 128 q/block; reg-prefetch + ds_write staging,
// pad-76 tiles (38 dw stride -> ~2-way conflicts, free). blockIdx.z = key-split;
// no-rescale softmax -> partials combine by plain addition (in gemm_proj).
__global__ __launch_bounds__(256) void attn_kernel(const _Float16* __restrict__ qb,
                                                   const _Float16* __restrict__ kb,
                                                   const _Float16* __restrict__ vtb,
                                                   __fp16* __restrict__ opart,
                                                   float* __restrict__ lpart) {
  __shared__ __align__(16) u16 lk[2][64 * PADK];   // K-tile [key][d]
  __shared__ __align__(16) u16 lv[2][64 * PADK];   // V^T-tile [d][key]
  int bh = blockIdx.y, qblk = blockIdx.x, ks = blockIdx.z;
  int tid = threadIdx.x, lane = tid & 63, wave = tid >> 6;
  int quad = lane >> 4, l16 = lane & 15;

  const _Float16* q_bh = qb + (size_t)bh * NSEQ * HD;
  const u16* k_bh = (const u16*)(kb + (size_t)bh * NSEQ * HD);
  const u16* v_bh = (const u16*)(vtb + (size_t)bh * HD * NSEQ);

  // Q fragments (B-layout: n=l16, k=quad*8+j), 2 q-tiles per wave
  int q0 = qblk * 128 + wave * 32 + l16;
  f16x8 qf[2][2];
#pragma unroll
  for (int qt = 0; qt < 2; qt++) {
    const _Float16* qp = q_bh + (size_t)(q0 + qt * 16) * HD + quad * 8;
    qf[qt][0] = *(const f16x8*)qp;
    qf[qt][1] = *(const f16x8*)(qp + 32);
  }

  f32x4 o[2][4] = {};
  float l_i[2] = {0.f, 0.f};

  // staging: 64 rows x 8 chunks(16B), 2 rows/thread per buffer
  int srow = tid >> 3, scj = tid & 7;
  const u16* kp0 = k_bh + (size_t)srow * HD + scj * 8;
  const u16* kp1 = kp0 + (size_t)32 * HD;
  const u16* vp0 = v_bh + (size_t)srow * NSEQ + scj * 8;
  const u16* vp1 = vp0 + (size_t)32 * NSEQ;
  int w0 = srow * PADK + scj * 8, w1 = (srow + 32) * PADK + scj * 8;

  const int kt_beg = ks * (NSEQ / 64 / KSPLIT);        // 16 tiles per block
  const int kt_end = kt_beg + (NSEQ / 64 / KSPLIT);

  {  // prologue: stage first tile into buffer 0
    int k0 = kt_beg * 64;
    *(uint4*)(lk[0] + w0) = *(const uint4*)(kp0 + (size_t)k0 * HD);
    *(uint4*)(lk[0] + w1) = *(const uint4*)(kp1 + (size_t)k0 * HD);
    *(uint4*)(lv[0] + w0) = *(const uint4*)(vp0 + k0);
    *(uint4*)(lv[0] + w1) = *(const uint4*)(vp1 + k0);
  }

  for (int kt = kt_beg; kt < kt_end; kt++) {
    int cur = kt & 1, nxt = cur ^ 1;
    __syncthreads();

    uint4 rk0, rk1, rv0, rv1;
    if (kt < kt_end - 1) {
      int k0 = (kt + 1) * 64;
      rk0 = *(const uint4*)(kp0 + (size_t)k0 * HD);
      rk1 = *(const uint4*)(kp1 + (size_t)k0 * HD);
      rv0 = *(const uint4*)(vp0 + k0);
      rv1 = *(const uint4*)(vp1 + k0);
    }

    // S^T = K·Q^T : lane gets keys {16nt+quad*4+r}, query l16
    f32x4 s0[4], s1[4];
#pragma unroll
    for (int nt = 0; nt < 4; nt++) {
      const u16* kp = lk[cur] + (nt * 16 + l16) * PADK + quad * 8;
      f16x8 kf0 = *(const f16x8*)kp;
      f16x8 kf1 = *(const f16x8*)(kp + 32);
      f32x4 t0 = {}, t1 = {};
      t0 = __builtin_amdgcn_mfma_f32_16x16x32_f16(kf0, qf[0][0], t0, 0, 0, 0);
      t0 = __builtin_amdgcn_mfma_f32_16x16x32_f16(kf1, qf[0][1], t0, 0, 0, 0);
      t1 = __builtin_amdgcn_mfma_f32_16x16x32_f16(kf0, qf[1][0], t1, 0, 0, 0);
      t1 = __builtin_amdgcn_mfma_f32_16x16x32_f16(kf1, qf[1][1], t1, 0, 0, 0);
      s0[nt] = t0; s1[nt] = t1;
    }

    // p = 2^s (scale folded into q); l per-lane; P^T fragment straight to PV
#pragma unroll
    for (int nt = 0; nt < 4; nt++) {
      float a0 = __builtin_amdgcn_exp2f(s0[nt][0]);
      float a1 = __builtin_amdgcn_exp2f(s0[nt][1]);
      float a2 = __builtin_amdgcn_exp2f(s0[nt][2]);
      float a3 = __builtin_amdgcn_exp2f(s0[nt][3]);
      l_i[0] += (a0 + a1) + (a2 + a3);
      float b0 = __builtin_amdgcn_exp2f(s1[nt][0]);
      float b1 = __builtin_amdgcn_exp2f(s1[nt][1]);
      float b2 = __builtin_amdgcn_exp2f(s1[nt][2]);
      float b3 = __builtin_amdgcn_exp2f(s1[nt][3]);
      l_i[1] += (b0 + b1) + (b2 + b3);
      union { fp16x2 h2[2]; f16x4 h4; } pa, pb;
      pa.h2[0] = __builtin_amdgcn_cvt_pkrtz(a0, a1);
      pa.h2[1] = __builtin_amdgcn_cvt_pkrtz(a2, a3);
      pb.h2[0] = __builtin_amdgcn_cvt_pkrtz(b0, b1);
      pb.h2[1] = __builtin_amdgcn_cvt_pkrtz(b2, b3);
#pragma unroll
      for (int dt = 0; dt < 4; dt++) {
        f16x4 vf = *(const f16x4*)(lv[cur] + (dt * 16 + l16) * PADK + nt * 16 + quad * 4);
        o[0][dt] = MFMA_PV(vf, pa.h4, o[0][dt]);
        o[1][dt] = MFMA_PV(vf, pb.h4, o[1][dt]);
      }
    }

    if (kt < kt_end - 1) {
      *(uint4*)(lk[nxt] + w0) = rk0;
      *(uint4*)(lk[nxt] + w1) = rk1;
      *(uint4*)(lv[nxt] + w0) = rv0;
      *(uint4*)(lv[nxt] + w1) = rv1;
    }
  }

  // partial denominator: quads hold disjoint key subsets for query l16
#pragma unroll
  for (int qt = 0; qt < 2; qt++) {
    l_i[qt] += __shfl_xor(l_i[qt], 16);
    l_i[qt] += __shfl_xor(l_i[qt], 32);
  }

  int b = bh / H_DIM, h = bh % H_DIM;
  __fp16* obase = opart + (size_t)ks * M_ROWS * C_DIM;
  float* lrow = lpart + ((size_t)ks * H_DIM * 2 + bh) * NSEQ;
#pragma unroll
  for (int qt = 0; qt < 2; qt++) {
    int q = q0 + qt * 16;  // query index (l16-dependent)
    if (quad == 0) lrow[q] = l_i[qt];
    __fp16* orow = obase + (size_t)(b * NSEQ + q) * C_DIM + h * HD;
#pragma unroll
    for (int dt = 0; dt < 4; dt++) {
      union { fp16x2 h2[2]; fp16x4 h4; } ov;
      ov.h2[0] = __builtin_amdgcn_cvt_pkrtz(o[qt][dt][0], o[qt][dt][1]);
      ov.h2[1] = __builtin_amdgcn_cvt_pkrtz(o[qt][dt][2], o[qt][dt][3]);
      *(fp16x4*)(orow + dt * 16 + quad * 4) = ov.h4;  // O^T d=dt*16+quad*4+reg
    }
  }
}

extern "C" void kernel_launch(void* const* d_in, const int* in_sizes, int n_in,
                              void* d_out, int out_size, void* d_ws, size_t ws_size,
                              hipStream_t stream) {
  const float* x = (const float*)d_in[0];       // [2,2048,768]
  const float* w_qkv = (const float*)d_in[1];   // [768,2304]
  const float* w_proj = (const float*)d_in[2];  // [768,768]
  const float* b_proj = (const float*)d_in[3];  // [768]
  float* out = (float*)d_out;

  char* ws = (char*)d_ws;
  u16* x_bf        = (u16*)(ws);                  // 4096*768*2   = 6291456
  u16* wqkvT       = (u16*)(ws + 6291456);        // 2304*768*2   = 3538944
  __fp16* wprojT   = (__fp16*)(ws + 9830400);     // 768*768*2    = 1179648
  _Float16* qb     = (_Float16*)(ws + 11010048);  // 24*2048*64*2 = 6291456
  _Float16* kb     = (_Float16*)(ws + 17301504);
  _Float16* vtb    = (_Float16*)(ws + 23592960);  // ends at 29884416
  __fp16* opart    = (__fp16*)(ws + 29884416);    // 2*4096*768*2 = 12582912
  float* lpart     = (float*)(ws + 42467328);     // 2*24*2048*4  = 393216 -> ends 42860544

  prep_kernel<<<dim3(72, 24, 3), 256, 0, stream>>>(x, w_qkv, w_proj, x_bf, wqkvT, wprojT);
  gemm_qkv_kernel<<<dim3(32, 18), 256, 0, stream>>>(x_bf, wqkvT, qb, kb, vtb);
  attn_kernel<<<dim3(16, 24, KSPLIT), 256, 0, stream>>>(qb, kb, vtb, opart, lpart);
  gemm_proj_kernel<<<dim3(64, 6), 256, 0, stream>>>(opart, lpart, (const u16*)wprojT,
                                                    b_proj, out);
}

// Round 12
// 184.776 us; speedup vs baseline: 1.4042x; 1.0355x over previous
//
#include <hip/hip_runtime.h>

#define C_DIM 768
#define NSEQ 2048
#define H_DIM 12
#define HD 64
#define M_ROWS 4096   // B*N
#define KSPLIT 4      // each attn block handles NSEQ/KSPLIT keys

typedef float f32x4 __attribute__((ext_vector_type(4)));
typedef short bf16x8 __attribute__((ext_vector_type(8)));
typedef _Float16 f16x8 __attribute__((ext_vector_type(8)));
typedef _Float16 f16x4 __attribute__((ext_vector_type(4)));
typedef __fp16 fp16x2 __attribute__((ext_vector_type(2)));  // cvt_pkrtz return type
typedef __fp16 fp16x4 __attribute__((ext_vector_type(4)));
typedef __fp16 fp16x8 __attribute__((ext_vector_type(8)));
typedef unsigned short u16;

// NOTE: legacy K=16 f16 MFMA builtin has NO underscore before f16 on gfx950.
#define MFMA_PV(a, b, c) __builtin_amdgcn_mfma_f32_16x16x16f16(a, b, c, 0, 0, 0)

typedef unsigned int __attribute__((address_space(1))) as1_uint;
typedef unsigned int __attribute__((address_space(3))) as3_uint;
// async global->LDS DMA, 16B per lane; LDS dest = wave-uniform base + lane*16
__device__ __forceinline__ void dma16(const void* g, void* l) {
  __builtin_amdgcn_global_load_lds((const as1_uint*)g, (as3_uint*)l, 16, 0, 0);
}

__device__ __forceinline__ u16 f2bf(float f) {
  union { float f; unsigned u; } v; v.f = f;
  unsigned u = v.u + 0x7FFFu + ((v.u >> 16) & 1u);  // RNE
  return (u16)(u >> 16);
}

// ---------------- fused prep: weight transposes + x conversion ----------------
// z=0: w_qkv^T (bf16); z=1: w_proj^T (f16); z=2: x fp32->bf16
__global__ __launch_bounds__(256) void prep_kernel(const float* __restrict__ x,
                                                   const float* __restrict__ wq,
                                                   const float* __restrict__ wp,
                                                   u16* __restrict__ x_bf,
                                                   u16* __restrict__ outq,
                                                   __fp16* __restrict__ outp) {
  if (blockIdx.z == 2) {
    const int n4 = M_ROWS * C_DIM / 4;
    int lb = blockIdx.y * 72 + blockIdx.x;          // 0..1727
    int i0 = lb * 256 + threadIdx.x;                // < 442368
    {
      float4 v = ((const float4*)x)[i0];
      ushort4 o;
      o.x = f2bf(v.x); o.y = f2bf(v.y); o.z = f2bf(v.z); o.w = f2bf(v.w);
      ((ushort4*)x_bf)[i0] = o;
    }
    int i1 = i0 + 442368;
    if (i1 < n4) {
      float4 v = ((const float4*)x)[i1];
      ushort4 o;
      o.x = f2bf(v.x); o.y = f2bf(v.y); o.z = f2bf(v.z); o.w = f2bf(v.w);
      ((ushort4*)x_bf)[i1] = o;
    }
    return;
  }
  const int R = C_DIM;
  __shared__ float t[32][33];
  int tx = threadIdx.x & 31, ty = threadIdx.x >> 5;  // 32 x 8
  int c0 = blockIdx.x * 32, r0 = blockIdx.y * 32;
  if (blockIdx.z == 0) {
    const int Cc = 3 * C_DIM;
#pragma unroll
    for (int i = 0; i < 4; i++)
      t[ty + i * 8][tx] = wq[(size_t)(r0 + ty + i * 8) * Cc + c0 + tx];
    __syncthreads();
#pragma unroll
    for (int i = 0; i < 4; i++)
      outq[(size_t)(c0 + ty + i * 8) * R + r0 + tx] = f2bf(t[tx][ty + i * 8]);
  } else {
    if (blockIdx.x >= 24) return;
    const int Cc = C_DIM;
#pragma unroll
    for (int i = 0; i < 4; i++)
      t[ty + i * 8][tx] = wp[(size_t)(r0 + ty + i * 8) * Cc + c0 + tx];
    __syncthreads();
#pragma unroll
    for (int i = 0; i < 4; i++)
      outp[(size_t)(c0 + ty + i * 8) * R + r0 + tx] = (__fp16)t[tx][ty + i * 8];
  }
}

// ------- 128x128 bf16 MFMA GEMM core, double-buffered global_load_lds --------
// SWAPPED operands -> C^T: lane holds 4 consecutive output channels per token.
__device__ __forceinline__ void gemm_core_128_db(const u16* __restrict__ A,
                                                 const u16* __restrict__ BT,
                                                 int m0, int n0,
                                                 u16 (*la)[128 * 32], u16 (*lb)[128 * 32],
                                                 f32x4 acc[4][4]) {
  const int K = C_DIM;
  int tid = threadIdx.x, lane = tid & 63, wave = tid >> 6;
  int wm = (wave >> 1) * 64, wn = (wave & 1) * 64;
  int quad = lane >> 4, l16 = lane & 15;

  int r0 = wave * 16 + (lane >> 2);
  int sw = (((lane & 3) ^ (r0 & 3)) * 8);   // (r0+64)&3 == r0&3
  const u16* ga0 = A + (size_t)(m0 + r0) * K + sw;
  const u16* ga1 = A + (size_t)(m0 + r0 + 64) * K + sw;
  const u16* gb0 = BT + (size_t)(n0 + r0) * K + sw;
  const u16* gb1 = BT + (size_t)(n0 + r0 + 64) * K + sw;
  int ofs0 = wave * 16 * 32, ofs1 = ofs0 + 64 * 32;  // wave-uniform LDS offsets

  dma16(ga0, la[0] + ofs0);
  dma16(ga1, la[0] + ofs1);
  dma16(gb0, lb[0] + ofs0);
  dma16(gb1, lb[0] + ofs1);

  const int NT = K / 32;  // 24
  for (int kt = 0; kt < NT; kt++) {
    int cur = kt & 1, nxt = cur ^ 1;
    __syncthreads();
    if (kt < NT - 1) {
      int k0 = (kt + 1) * 32;
      dma16(ga0 + k0, la[nxt] + ofs0);
      dma16(ga1 + k0, la[nxt] + ofs1);
      dma16(gb0 + k0, lb[nxt] + ofs0);
      dma16(gb1 + k0, lb[nxt] + ofs1);
    }
    bf16x8 af[4], bfr[4];
#pragma unroll
    for (int mt = 0; mt < 4; mt++) {
      int r = wm + mt * 16 + l16;
      af[mt] = *(const bf16x8*)(la[cur] + r * 32 + ((quad ^ (r & 3)) * 8));
    }
#pragma unroll
    for (int nt = 0; nt < 4; nt++) {
      int r = wn + nt * 16 + l16;
      bfr[nt] = *(const bf16x8*)(lb[cur] + r * 32 + ((quad ^ (r & 3)) * 8));
    }
#pragma unroll
    for (int mt = 0; mt < 4; mt++)
#pragma unroll
      for (int nt = 0; nt < 4; nt++)   // SWAPPED: C^T
        acc[mt][nt] = __builtin_amdgcn_mfma_f32_16x16x32_bf16(bfr[nt], af[mt], acc[mt][nt], 0, 0, 0);
  }
}

// ---------------- GEMM1: qkv = x @ w_qkv, scatter into f16 q/k/v^T ----------------
// C^T layout: lane has 4 consecutive channels (gn0..gn0+3) for one token gm.
#define Q_PRESCALE 0.18033688011112042f  // HD^-0.5 * log2(e)
__global__ __launch_bounds__(256) void gemm_qkv_kernel(const u16* __restrict__ A,
                                                       const u16* __restrict__ BT,
                                                       _Float16* __restrict__ qb,
                                                       _Float16* __restrict__ kb,
                                                       _Float16* __restrict__ vtb) {
  __shared__ __align__(16) u16 la[2][128 * 32];
  __shared__ __align__(16) u16 lb[2][128 * 32];
  f32x4 acc[4][4] = {};
  int m0 = blockIdx.x * 128, n0 = blockIdx.y * 128;
  gemm_core_128_db(A, BT, m0, n0, la, lb, acc);

  int lane = threadIdx.x & 63, wave = threadIdx.x >> 6;
  int wm = (wave >> 1) * 64, wn = (wave & 1) * 64;
  int quad = lane >> 4, l16 = lane & 15;
#pragma unroll
  for (int mt = 0; mt < 4; mt++) {
#pragma unroll
    for (int nt = 0; nt < 4; nt++) {
      int gm = m0 + wm + mt * 16 + l16;        // token 0..4095
      int b = gm >> 11, n = gm & 2047;
      int gn0 = n0 + wn + nt * 16 + quad * 4;  // channel base, 4-aligned
      int which = gn0 / C_DIM;                 // uniform per block
      int cc = gn0 - which * C_DIM;
      int h = cc >> 6, d0 = cc & 63;           // 4-block never crosses head bdry
      size_t bh = (size_t)(b * H_DIM + h);
      if (which == 2) {
#pragma unroll
        for (int r = 0; r < 4; r++)
          vtb[(bh * HD + d0 + r) * NSEQ + n] = (_Float16)acc[mt][nt][r];  // v^T
      } else if (which == 0) {
        f16x4 hv;
#pragma unroll
        for (int r = 0; r < 4; r++) hv[r] = (_Float16)(acc[mt][nt][r] * Q_PRESCALE);
        *(f16x4*)(qb + (bh * NSEQ + n) * HD + d0) = hv;   // 4 consecutive d
      } else {
        f16x4 hv;
#pragma unroll
        for (int r = 0; r < 4; r++) hv[r] = (_Float16)acc[mt][nt][r];
        *(f16x4*)(kb + (bh * NSEQ + n) * HD + d0) = hv;
      }
    }
  }
}

// ------- GEMM3 fused with combine: out = (sum_ks o / sum_ks l) @ w_proj + b -------
// 64x128 tiles, C^T accumulators -> float4 output stores + float4 bias loads.
__global__ __launch_bounds__(256) void gemm_proj_kernel(const __fp16* __restrict__ opart,
                                                        const float* __restrict__ lpart,
                                                        const u16* __restrict__ BT,
                                                        const float* __restrict__ bias,
                                                        float* __restrict__ out) {
  __shared__ __align__(16) u16 la[2][64 * 32];
  __shared__ __align__(16) u16 lb[2][128 * 32];
  int tid = threadIdx.x, lane = tid & 63, wave = tid >> 6;
  int quad = lane >> 4, l16 = lane & 15;
  int wm = (wave >> 1) * 32, wn = (wave & 1) * 64;
  int m0 = blockIdx.x * 64, n0 = blockIdx.y * 128;

  // B DMA geometry
  int r0 = wave * 16 + (lane >> 2);
  int swb = (((lane & 3) ^ (r0 & 3)) * 8);
  const u16* gb0 = BT + (size_t)(n0 + r0) * C_DIM + swb;
  const u16* gb1 = BT + (size_t)(n0 + r0 + 64) * C_DIM + swb;
  int ofsB0 = wave * 16 * 32, ofsB1 = ofsB0 + 64 * 32;

  // A staging role: row ar (0..63), chunk cj (0..3); combine KSPLIT partials
  int ar = r0, cj = lane & 3;
  int m = m0 + ar;
  int bb = m >> 11, q = m & 2047;
  const __fp16* ap = opart + (size_t)m * C_DIM + cj * 8;
  int wslotA = ar * 32 + ((cj ^ (ar & 3)) * 8);

  f32x4 acc[2][4] = {};
  union pk_t { fp16x2 h2[4]; uint4 v; };

#define COMBINE_A(dstbuf, k0, hh)                                              \
  {                                                                            \
    float fs[8] = {0, 0, 0, 0, 0, 0, 0, 0};                                    \
    float l = 0.f;                                                             \
    _Pragma("unroll") for (int kk = 0; kk < KSPLIT; kk++) {                    \
      fp16x8 pv = *(const fp16x8*)(ap + (size_t)kk * M_ROWS * C_DIM + (k0));   \
      _Pragma("unroll") for (int j = 0; j < 8; j++) fs[j] += (float)pv[j];     \
      l += lpart[((size_t)kk * H_DIM * 2 + bb * H_DIM + (hh)) * NSEQ + q];     \
    }                                                                          \
    float inv = 1.f / l;                                                       \
    pk_t w;                                                                    \
    _Pragma("unroll") for (int j = 0; j < 4; j++)                              \
        w.h2[j] = __builtin_amdgcn_cvt_pkrtz(fs[2 * j] * inv, fs[2 * j + 1] * inv); \
    *(uint4*)(la[dstbuf] + wslotA) = w.v;                                      \
  }

  // prologue: tile 0
  dma16(gb0, lb[0] + ofsB0);
  dma16(gb1, lb[0] + ofsB1);
  COMBINE_A(0, 0, 0);

  const int NT = C_DIM / 32;  // 24
  for (int kt = 0; kt < NT; kt++) {
    int cur = kt & 1, nxt = cur ^ 1;
    __syncthreads();
    if (kt < NT - 1) {
      int k0 = (kt + 1) * 32;
      dma16(gb0 + k0, lb[nxt] + ofsB0);
      dma16(gb1 + k0, lb[nxt] + ofsB1);
      COMBINE_A(nxt, k0, (kt + 1) >> 1);
    }
    f16x8 af[2], bf[4];
#pragma unroll
    for (int mt = 0; mt < 2; mt++) {
      int r = wm + mt * 16 + l16;
      af[mt] = *(const f16x8*)(la[cur] + r * 32 + ((quad ^ (r & 3)) * 8));
    }
#pragma unroll
    for (int nt = 0; nt < 4; nt++) {
      int r = wn + nt * 16 + l16;
      bf[nt] = *(const f16x8*)(lb[cur] + r * 32 + ((quad ^ (r & 3)) * 8));
    }
#pragma unroll
    for (int mt = 0; mt < 2; mt++)
#pragma unroll
      for (int nt = 0; nt < 4; nt++)   // SWAPPED: C^T
        acc[mt][nt] = __builtin_amdgcn_mfma_f32_16x16x32_f16(bf[nt], af[mt], acc[mt][nt], 0, 0, 0);
  }

#pragma unroll
  for (int mt = 0; mt < 2; mt++) {
#pragma unroll
    for (int nt = 0; nt < 4; nt++) {
      int gm = m0 + wm + mt * 16 + l16;
      int gn0 = n0 + wn + nt * 16 + quad * 4;
      float4 bv = *(const float4*)(bias + gn0);
      float4 o4;
      o4.x = acc[mt][nt][0] + bv.x;
      o4.y = acc[mt][nt][1] + bv.y;
      o4.z = acc[mt][nt][2] + bv.z;
      o4.w = acc[mt][nt][3] + bv.w;
      *(float4*)(out + (size_t)gm * C_DIM + gn0) = o4;
    }
  }
}

// ---------------- flash attention, S^T, swizzled stride-64 tiles ----------------
// 256 thr, 4 waves x 4 q-tiles = 256 q/block; KSPLIT=4 -> grid 8x24x4 = 768 =
// 3 blocks/CU. V-frag reads + staging amortized over 2x more queries than R9.
// LDS tiles [64][64] u16, slot = chunk ^ (row&7): 16B-aligned accesses,
// conflict-free staging writes, 2-way (free) K-frag b128 reads.
__global__ __launch_bounds__(256) void attn_kernel(const _Float16* __restrict__ qb,
                                                   const _Float16* __restrict__ kb,
                                                   const _Float16* __restrict__ vtb,
                                                   __fp16* __restrict__ opart,
                                                   float* __restrict__ lpart) {
  __shared__ __align__(16) u16 lk[2][64 * 64];   // K-tile [key][d], swizzled
  __shared__ __align__(16) u16 lv[2][64 * 64];   // V^T-tile [d][key], swizzled
  int bh = blockIdx.y, qblk = blockIdx.x, ks = blockIdx.z;
  int tid = threadIdx.x, lane = tid & 63, wave = tid >> 6;
  int quad = lane >> 4, l16 = lane & 15;

  const _Float16* q_bh = qb + (size_t)bh * NSEQ * HD;
  const u16* k_bh = (const u16*)(kb + (size_t)bh * NSEQ * HD);
  const u16* v_bh = (const u16*)(vtb + (size_t)bh * HD * NSEQ);

  // Q fragments (B-layout: n=l16, k=quad*8+j), 4 q-tiles per wave
  int q0 = qblk * 256 + wave * 64 + l16;
  f16x8 qf[4][2];
#pragma unroll
  for (int qt = 0; qt < 4; qt++) {
    const _Float16* qp = q_bh + (size_t)(q0 + qt * 16) * HD + quad * 8;
    qf[qt][0] = *(const f16x8*)qp;
    qf[qt][1] = *(const f16x8*)(qp + 32);
  }

  f32x4 o[4][4] = {};
  float l_i[4] = {0.f, 0.f, 0.f, 0.f};

  // staging: 64 rows x 8 chunks(16B), 2 rows/thread per buffer; LDS slot
  // swizzled by row&7 (srow and srow+32 share row&7? (srow+32)&7 == srow&7? 32&7=0 yes)
  int srow = tid >> 3, scj = tid & 7;
  const u16* kp0 = k_bh + (size_t)srow * HD + scj * 8;
  const u16* kp1 = kp0 + (size_t)32 * HD;
  const u16* vp0 = v_bh + (size_t)srow * NSEQ + scj * 8;
  const u16* vp1 = vp0 + (size_t)32 * NSEQ;
  int slot = (scj ^ (srow & 7)) * 8;
  int w0 = srow * 64 + slot, w1 = (srow + 32) * 64 + slot;

  const int kt_beg = ks * (NSEQ / 64 / KSPLIT);        // 8 tiles per block
  const int kt_end = kt_beg + (NSEQ / 64 / KSPLIT);

  {  // prologue: stage first tile into buffer 0
    int k0 = kt_beg * 64;
    *(uint4*)(lk[0] + w0) = *(const uint4*)(kp0 + (size_t)k0 * HD);
    *(uint4*)(lk[0] + w1) = *(const uint4*)(kp1 + (size_t)k0 * HD);
    *(uint4*)(lv[0] + w0) = *(const uint4*)(vp0 + k0);
    *(uint4*)(lv[0] + w1) = *(const uint4*)(vp1 + k0);
  }

  for (int kt = kt_beg; kt < kt_end; kt++) {
    int cur = kt & 1, nxt = cur ^ 1;
    __syncthreads();

    uint4 rk0, rk1, rv0, rv1;
    if (kt < kt_end - 1) {
      int k0 = (kt + 1) * 64;
      rk0 = *(const uint4*)(kp0 + (size_t)k0 * HD);
      rk1 = *(const uint4*)(kp1 + (size_t)k0 * HD);
      rv0 = *(const uint4*)(vp0 + k0);
      rv1 = *(const uint4*)(vp1 + k0);
    }

    int rs = l16 & 7;  // row&7 for all fragment rows (16·x + l16)
#pragma unroll
    for (int nt = 0; nt < 4; nt++) {
      // K fragment: row nt*16+l16, chunks quad and quad+4 (swizzled)
      const u16* kbp = lk[cur] + (nt * 16 + l16) * 64;
      f16x8 kf0 = *(const f16x8*)(kbp + ((quad ^ rs) * 8));
      f16x8 kf1 = *(const f16x8*)(kbp + (((quad + 4) ^ rs) * 8));
      // S^T = K·Q^T : lane gets keys {nt*16+quad*4+r}, query l16
      f32x4 s[4];
#pragma unroll
      for (int qt = 0; qt < 4; qt++) {
        f32x4 t = {};
        t = __builtin_amdgcn_mfma_f32_16x16x32_f16(kf0, qf[qt][0], t, 0, 0, 0);
        t = __builtin_amdgcn_mfma_f32_16x16x32_f16(kf1, qf[qt][1], t, 0, 0, 0);
        s[qt] = t;
      }
      // p = 2^s (scale folded into q); l per-lane; P^T straight to PV B-operand
      f16x4 p[4];
#pragma unroll
      for (int qt = 0; qt < 4; qt++) {
        float e0 = __builtin_amdgcn_exp2f(s[qt][0]);
        float e1 = __builtin_amdgcn_exp2f(s[qt][1]);
        float e2 = __builtin_amdgcn_exp2f(s[qt][2]);
        float e3 = __builtin_amdgcn_exp2f(s[qt][3]);
        l_i[qt] += (e0 + e1) + (e2 + e3);
        union { fp16x2 h2[2]; f16x4 h4; } u;
        u.h2[0] = __builtin_amdgcn_cvt_pkrtz(e0, e1);
        u.h2[1] = __builtin_amdgcn_cvt_pkrtz(e2, e3);
        p[qt] = u.h4;
      }
      // V fragments: row dt*16+l16, col nt*16+quad*4 -> chunk nt*2+(quad>>1)
#pragma unroll
      for (int dt = 0; dt < 4; dt++) {
        int c = nt * 2 + (quad >> 1);
        f16x4 vf = *(const f16x4*)(lv[cur] + (dt * 16 + l16) * 64 +
                                   ((c ^ rs) * 8) + (quad & 1) * 4);
#pragma unroll
        for (int qt = 0; qt < 4; qt++)
          o[qt][dt] = MFMA_PV(vf, p[qt], o[qt][dt]);
      }
    }

    if (kt < kt_end - 1) {
      *(uint4*)(lk[nxt] + w0) = rk0;
      *(uint4*)(lk[nxt] + w1) = rk1;
      *(uint4*)(lv[nxt] + w0) = rv0;
      *(uint4*)(lv[nxt] + w1) = rv1;
    }
  }

  // partial denominator: quads hold disjoint key subsets for query l16
#pragma unroll
  for (int qt = 0; qt < 4; qt++) {
    l_i[qt] += __shfl_xor(l_i[qt], 16);
    l_i[qt] += __shfl_xor(l_i[qt], 32);
  }

  int b = bh / H_DIM, h = bh % H_DIM;
  __fp16* obase = opart + (size_t)ks * M_ROWS * C_DIM;
  float* lrow = lpart + ((size_t)ks * H_DIM * 2 + bh) * NSEQ;
#pragma unroll
  for (int qt = 0; qt < 4; qt++) {
    int q = q0 + qt * 16;  // query index (l16-dependent)
    if (quad == 0) lrow[q] = l_i[qt];
    __fp16* orow = obase + (size_t)(b * NSEQ + q) * C_DIM + h * HD;
#pragma unroll
    for (int dt = 0; dt < 4; dt++) {
      union { fp16x2 h2[2]; fp16x4 h4; } ov;
      ov.h2[0] = __builtin_amdgcn_cvt_pkrtz(o[qt][dt][0], o[qt][dt][1]);
      ov.h2[1] = __builtin_amdgcn_cvt_pkrtz(o[qt][dt][2], o[qt][dt][3]);
      *(fp16x4*)(orow + dt * 16 + quad * 4) = ov.h4;  // O^T d=dt*16+quad*4+reg
    }
  }
}

extern "C" void kernel_launch(void* const* d_in, const int* in_sizes, int n_in,
                              void* d_out, int out_size, void* d_ws, size_t ws_size,
                              hipStream_t stream) {
  const float* x = (const float*)d_in[0];       // [2,2048,768]
  const float* w_qkv = (const float*)d_in[1];   // [768,2304]
  const float* w_proj = (const float*)d_in[2];  // [768,768]
  const float* b_proj = (const float*)d_in[3];  // [768]
  float* out = (float*)d_out;

  char* ws = (char*)d_ws;
  u16* x_bf        = (u16*)(ws);                  // 4096*768*2   = 6291456
  u16* wqkvT       = (u16*)(ws + 6291456);        // 2304*768*2   = 3538944
  __fp16* wprojT   = (__fp16*)(ws + 9830400);     // 768*768*2    = 1179648
  _Float16* qb     = (_Float16*)(ws + 11010048);  // 24*2048*64*2 = 6291456
  _Float16* kb     = (_Float16*)(ws + 17301504);
  _Float16* vtb    = (_Float16*)(ws + 23592960);  // ends at 29884416
  __fp16* opart    = (__fp16*)(ws + 29884416);    // 4*4096*768*2 = 25165824
  float* lpart     = (float*)(ws + 55050240);     // 4*24*2048*4  = 786432 -> ends 55836672

  prep_kernel<<<dim3(72, 24, 3), 256, 0, stream>>>(x, w_qkv, w_proj, x_bf, wqkvT, wprojT);
  gemm_qkv_kernel<<<dim3(32, 18), 256, 0, stream>>>(x_bf, wqkvT, qb, kb, vtb);
  attn_kernel<<<dim3(8, 24, KSPLIT), 256, 0, stream>>>(qb, kb, vtb, opart, lpart);
  gemm_proj_kernel<<<dim3(64, 6), 256, 0, stream>>>(opart, lpart, (const u16*)wprojT,
                                                    b_proj, out);
}